// Round 6
// baseline (680.458 us; speedup 1.0000x reference)
//
#include <hip/hip_runtime.h>

typedef unsigned short u16;
typedef unsigned int u32;
typedef __bf16 bf16x8 __attribute__((ext_vector_type(8)));
typedef float f32x4 __attribute__((ext_vector_type(4)));

#define N 4096
#define KD 128
#define G 4              // cols per lane
#define W 256            // strip width (u16); 512B per row
#define CH 32            // rows per block
#define NCHUNK 128       // N/CH
#define NBLK 130         // ceil((N+63)/CH)
#define TOTSTEP 4159     // N + 63
#define WINROWS 128      // rolling window rows (4 slots x 32)
#define WINB 65536       // WINROWS*512
#define HUGEV 3.0e38f
#define TS 128
#define PADK 136
#define PSTRIDE 32       // prog padded to 128B

__device__ __forceinline__ u16 f2bf(float v) {
  u32 u = __float_as_uint(v);
  u += 0x7fffu + ((u >> 16) & 1u);   // RNE
  return (u16)(u >> 16);
}
__device__ __forceinline__ float bf2f(u16 b) { return __uint_as_float(((u32)b) << 16); }
__device__ __forceinline__ float bfround(float v) { return bf2f(f2bf(v)); }

__device__ __forceinline__ float dpp_shr1(float oldv, float src) {
  return __int_as_float(__builtin_amdgcn_update_dpp(
      __float_as_int(oldv), __float_as_int(src), 0x138, 0xF, 0xF, false));
}

__device__ __forceinline__ void gload_lds16(const void* g, void* l) {
  __builtin_amdgcn_global_load_lds((const __attribute__((address_space(1))) u32*)g,
                                   (__attribute__((address_space(3))) u32*)l, 16, 0, 0);
}

// ---------------- norms (of bf16-rounded points) + flag init ----------------
__global__ __launch_bounds__(256) void norms_kernel(const float* __restrict__ pred,
                                                    const float* __restrict__ tgt,
                                                    float* __restrict__ na, float* __restrict__ nb,
                                                    int* __restrict__ prog) {
  if (blockIdx.x == 0 && threadIdx.x < 16) prog[threadIdx.x * PSTRIDE] = 0;
  int gw = blockIdx.x * 4 + (threadIdx.x >> 6);
  int lane = threadIdx.x & 63;
  const float* base = (gw < N) ? (pred + (size_t)gw * KD) : (tgt + (size_t)(gw - N) * KD);
  float2 v = ((const float2*)base)[lane];
  float x = bfround(v.x), y = bfround(v.y);
  float s = x * x + y * y;
  #pragma unroll
  for (int off = 32; off > 0; off >>= 1) s += __shfl_xor(s, off);
  if (lane == 0) { if (gw < N) na[gw] = s; else nb[gw - N] = s; }
}

// ---------------- C2 = |a|^2 + |b|^2 - 2 a.b  (bf16 out) ----------------
__global__ __launch_bounds__(256) void gemm_kernel(const float* __restrict__ A, const float* __restrict__ B,
                                                   const float* __restrict__ na, const float* __restrict__ nb,
                                                   u16* __restrict__ C2) {
  __shared__ u16 As[TS * PADK];
  __shared__ u16 Bs[TS * PADK];
  const int bi = blockIdx.y, bj = blockIdx.x;
  const int tid = threadIdx.x;
  {
    int row = tid >> 1, half = (tid & 1) * 64;
    const float* ga = A + (size_t)(bi * TS + row) * KD + half;
    const float* gb = B + (size_t)(bj * TS + row) * KD + half;
    u16* la = As + row * PADK + half;
    u16* lb = Bs + row * PADK + half;
    #pragma unroll
    for (int v = 0; v < 16; ++v) {
      float4 fa = ((const float4*)ga)[v];
      float4 fb = ((const float4*)gb)[v];
      *(ushort4*)(la + v * 4) = make_ushort4(f2bf(fa.x), f2bf(fa.y), f2bf(fa.z), f2bf(fa.w));
      *(ushort4*)(lb + v * 4) = make_ushort4(f2bf(fb.x), f2bf(fb.y), f2bf(fb.z), f2bf(fb.w));
    }
  }
  __syncthreads();
  const int wid = tid >> 6, lane = tid & 63;
  const int wr = (wid >> 1) * 64, wc = (wid & 1) * 64;
  const int l15 = lane & 15, l4 = lane >> 4;
  f32x4 acc[4][4] = {};
  #pragma unroll
  for (int ks = 0; ks < 4; ++ks) {
    bf16x8 af[4], bq[4];
    const int ko = ks * 32 + l4 * 8;
    #pragma unroll
    for (int m = 0; m < 4; ++m) af[m] = *(const bf16x8*)(As + (wr + m * 16 + l15) * PADK + ko);
    #pragma unroll
    for (int n = 0; n < 4; ++n) bq[n] = *(const bf16x8*)(Bs + (wc + n * 16 + l15) * PADK + ko);
    #pragma unroll
    for (int m = 0; m < 4; ++m)
      #pragma unroll
      for (int n = 0; n < 4; ++n)
        acc[m][n] = __builtin_amdgcn_mfma_f32_16x16x32_bf16(af[m], bq[n], acc[m][n], 0, 0, 0);
  }
  #pragma unroll
  for (int m = 0; m < 4; ++m) {
    const int r0 = bi * TS + wr + m * 16 + l4 * 4;
    #pragma unroll
    for (int n = 0; n < 4; ++n) {
      const int col = bj * TS + wc + n * 16 + l15;
      const float nbv = nb[col];
      #pragma unroll
      for (int e = 0; e < 4; ++e) {
        const int r = r0 + e;
        float d2v = fmaxf(na[r] + nbv - 2.0f * acc[m][n][e], 0.0f);
        C2[(size_t)r * N + col] = f2bf(d2v);
      }
    }
  }
}

// ---------------- wavefront DP over squared distances ----------------
// 8 WGs x 2 waves; wave owns a 256-col strip; intra-WG handoff via LDS ring,
// inter-WG via global edge + RMW flags.
#define STEP_F(CU, EV) { \
  const float c0 = bf2f((CU).x), c1 = bf2f((CU).y), c2 = bf2f((CU).z), c3 = bf2f((CU).w); \
  const float Lc = dpp_shr1((EV), D3); \
  const float h0 = fmaxf(fminf(D0, Lp), c0); \
  const float h1 = fmaxf(fminf(D1, D0), c1); \
  const float h2 = fmaxf(fminf(D2, D1), c2); \
  const float h3 = fmaxf(fminf(D3, D2), c3); \
  float x = __builtin_amdgcn_fmed3f(Lc, c0, h0); D0 = x; \
  x = __builtin_amdgcn_fmed3f(x, c1, h1); D1 = x; \
  x = __builtin_amdgcn_fmed3f(x, c2, h2); D2 = x; \
  x = __builtin_amdgcn_fmed3f(x, c3, h3); D3 = x; \
  Lp = Lc; \
}

#define LDGRP(IX, GG) { \
  const int eo = (s_lo + 8 * (GG)) & emask; \
  ea2[IX] = *(const float4*)(esrc + eo); \
  eb2[IX] = *(const float4*)(esrc + eo + 4); \
  cv[IX][0] = *(const ushort4*)(clb + cbs); \
  cv[IX][1] = *(const ushort4*)(clb + cbs + 512); \
  cv[IX][2] = *(const ushort4*)(clb + cbs + 1024); \
  cv[IX][3] = *(const ushort4*)(clb + cbs + 1536); \
  cv[IX][4] = *(const ushort4*)(clb + cbs + 2048); \
  cv[IX][5] = *(const ushort4*)(clb + cbs + 2560); \
  cv[IX][6] = *(const ushort4*)(clb + cbs + 3072); \
  cv[IX][7] = *(const ushort4*)(clb + cbs + 3584); \
  cbs += 4096; if (cbs >= WINB) cbs -= WINB; \
}

#define CGRP(IX) { \
  float t0, t1, t2, t3, t4, t5, t6, t7; \
  STEP_F(cv[IX][0], ea2[IX].x); t0 = D3; \
  STEP_F(cv[IX][1], ea2[IX].y); t1 = D3; \
  STEP_F(cv[IX][2], ea2[IX].z); t2 = D3; \
  STEP_F(cv[IX][3], ea2[IX].w); t3 = D3; \
  STEP_F(cv[IX][4], eb2[IX].x); t4 = D3; \
  STEP_F(cv[IX][5], eb2[IX].y); t5 = D3; \
  STEP_F(cv[IX][6], eb2[IX].z); t6 = D3; \
  STEP_F(cv[IX][7], eb2[IX].w); t7 = D3; \
  if (wr63) { \
    *(float*)((char*)ringw + ( ewb       & 511)) = t0; \
    *(float*)((char*)ringw + ((ewb +  4) & 511)) = t1; \
    *(float*)((char*)ringw + ((ewb +  8) & 511)) = t2; \
    *(float*)((char*)ringw + ((ewb + 12) & 511)) = t3; \
    *(float*)((char*)ringw + ((ewb + 16) & 511)) = t4; \
    *(float*)((char*)ringw + ((ewb + 20) & 511)) = t5; \
    *(float*)((char*)ringw + ((ewb + 24) & 511)) = t6; \
    *(float*)((char*)ringw + ((ewb + 28) & 511)) = t7; \
  } \
  ewb += 32; \
}

__global__ __launch_bounds__(128) void dp_kernel(const u16* __restrict__ C2, float* __restrict__ edgeG,
                                                 int* __restrict__ progG, float* __restrict__ out) {
  __shared__ u16 winbuf[2][136 * 256];                 // 2 x 69632B rolling windows
  __shared__ __align__(16) float ering0[128];          // wave0 -> wave1 row ring
  __shared__ __align__(16) float ering1[128];          // wave1 private staging ring
  __shared__ __align__(16) float einG[32];             // wave0 global-edge input
  __shared__ int prodcnt0, conscnt0;

  const int w = blockIdx.x;
  const int tid = threadIdx.x, wv = tid >> 6, lane = tid & 63;
  const int S = 2 * w + wv;
  const u16* cbase = C2 + (size_t)S * W;
  u16* win = winbuf[wv];
  const char* clb = (const char*)win;
  float* ringw = wv ? ering1 : ering0;
  const bool prodrole = (wv == 0) || (w < 7);
  const bool wr63 = prodrole && (lane == 63);
  float* esrc = wv ? ering0 : einG;
  const int emask = wv ? 127 : 31;
  const bool s0 = (S == 0);

  if (tid == 0) { prodcnt0 = 0; conscnt0 = 0; }
  if (w == 0 && wv == 0 && lane < 32) einG[lane] = (lane == 0) ? -HUGEV : HUGEV;
  __syncthreads();

  float D0 = HUGEV, D1 = HUGEV, D2 = HUGEV, D3 = HUGEV, Lp = HUGEV;

  auto STAGE = [&](int c) {
    const int lrow = lane >> 5, lcol = (lane & 31) * 8;
    const u16* g0 = cbase + (size_t)(c * CH + lrow) * N + lcol;
    u16* l0 = win + ((c * CH) & 127) * 256;
    #pragma unroll
    for (int n = 0; n < 16; ++n) gload_lds16(g0 + (size_t)(2 * n) * N, l0 + n * 512);
    if (((c * CH) & 127) == 0) {   // mirror rows 128..135 duplicate slot rows 0..7
      u16* lm = win + 128 * 256;
      #pragma unroll
      for (int n = 0; n < 4; ++n) gload_lds16(g0 + (size_t)(2 * n) * N, lm + n * 512);
    }
  };

  STAGE(0);   // one-time exposed staging latency

  for (int q = 0; q < NBLK; ++q) {
    const int s_lo = q * CH;
    const int s_hi = (s_lo + CH < TOTSTEP) ? (s_lo + CH) : TOTSTEP;

    // ---- consumer wait ----
    if (q <= 127) {
      if (wv == 1) {
        // need ring rows through q*32+31; wave0 block q' covers rows <= q'*32-32
        // => q' >= q+2 done => prodcnt0 >= q+3.  (q+2 here was the round-5 bug.)
        int it = 0;
        while (__hip_atomic_load(&prodcnt0, __ATOMIC_ACQUIRE, __HIP_MEMORY_SCOPE_WORKGROUP) < q + 3) {
          __builtin_amdgcn_s_sleep(1);
          if (++it > (1 << 22)) break;
        }
      } else if (w > 0) {
        if (lane == 0) {
          int it = 0;
          int* pg = progG + (w - 1) * PSTRIDE;
          while (__hip_atomic_fetch_add(pg, 0, __ATOMIC_RELAXED, __HIP_MEMORY_SCOPE_AGENT) < q + 1) {
            __builtin_amdgcn_s_sleep(2);
            if (++it > (1 << 22)) break;
          }
        }
      }
    }
    // ---- producer flow control (wave0 ring depth 4) ----
    if (wv == 0 && q >= 5) {
      int it = 0;
      while (__hip_atomic_load(&conscnt0, __ATOMIC_RELAXED, __HIP_MEMORY_SCOPE_WORKGROUP) < q - 4) {
        __builtin_amdgcn_s_sleep(1);
        if (++it > (1 << 22)) break;
      }
    }

    // ---- drain STAGE(q) ----
    asm volatile("s_waitcnt vmcnt(0)" ::: "memory");
    __builtin_amdgcn_sched_barrier(0);

    // ---- edge fill (wave0 global consumer) + issue STAGE(q+1) ----
    const int nst = (q + 1 < NCHUNK) ? ((((q + 1) * CH) & 127) == 0 ? 20 : 16) : 0;
    if (wv == 0 && w > 0 && q <= 127) {
      float ev = HUGEV;
      if (lane < 32)
        ev = __hip_atomic_load(edgeG + (size_t)(w - 1) * N + s_lo + lane,
                               __ATOMIC_RELAXED, __HIP_MEMORY_SCOPE_AGENT);
      __builtin_amdgcn_sched_barrier(0);
      if (q + 1 < NCHUNK) STAGE(q + 1);
      __builtin_amdgcn_sched_barrier(0);
      if (nst == 16)      asm volatile("s_waitcnt vmcnt(16)" ::: "memory");
      else if (nst == 20) asm volatile("s_waitcnt vmcnt(20)" ::: "memory");
      else                asm volatile("s_waitcnt vmcnt(0)" ::: "memory");
      if (lane < 32) einG[lane] = ev;
    } else {
      if (q + 1 < NCHUNK) STAGE(q + 1);
    }
    if (s0 && wv == 0 && q == 1 && lane == 0) einG[0] = HUGEV;   // drop row-0 seed
    asm volatile("s_waitcnt lgkmcnt(0)" ::: "memory");
    __builtin_amdgcn_sched_barrier(0);

    // ---- compute ----
    u32 cbs = (((u32)(s_lo - lane)) & 127) * 512 + lane * 8;
    int ewb = (((s_lo - 63) & 127)) * 4;

    if (q >= 2 && q <= 127) {
      ushort4 cv[2][8];
      float4 ea2[2], eb2[2];
      LDGRP(0, 0)
      LDGRP(1, 1)
      CGRP(0)
      LDGRP(0, 2)
      CGRP(1)
      LDGRP(1, 3)
      CGRP(0)
      CGRP(1)
    } else {
      for (int s = s_lo; s < s_hi; ++s) {
        const ushort4 cu = *(const ushort4*)(clb + cbs);
        cbs += 512; if (cbs >= WINB) cbs -= WINB;
        const float ev = esrc[s & emask];
        const float c0 = bf2f(cu.x), c1 = bf2f(cu.y), c2 = bf2f(cu.z), c3 = bf2f(cu.w);
        const float Lc = dpp_shr1(ev, D3);
        const float h0 = fmaxf(fminf(D0, Lp), c0);
        const float h1 = fmaxf(fminf(D1, D0), c1);
        const float h2 = fmaxf(fminf(D2, D1), c2);
        const float h3 = fmaxf(fminf(D3, D2), c3);
        float x = __builtin_amdgcn_fmed3f(Lc, c0, h0);
        const float n0 = x;
        x = __builtin_amdgcn_fmed3f(x, c1, h1);
        const float n1 = x;
        x = __builtin_amdgcn_fmed3f(x, c2, h2);
        const float n2 = x;
        x = __builtin_amdgcn_fmed3f(x, c3, h3);
        const float n3 = x;
        const int ii = s - lane;
        const bool act = (u32)ii < (u32)N;
        Lp = (s0 && lane == 0) ? HUGEV : Lc;
        if (act) { D0 = n0; D1 = n1; D2 = n2; D3 = n3; }
        const int ie = s - 63;
        if (wr63 && ie >= 0) *(float*)((char*)ringw + ((ie & 127) * 4)) = n3;
      }
    }

    // ---- publish ----
    if (wv == 0) {
      if (lane == 0)
        __hip_atomic_store(&prodcnt0, q + 1, __ATOMIC_RELEASE, __HIP_MEMORY_SCOPE_WORKGROUP);
    } else {
      if (lane == 0)
        __hip_atomic_store(&conscnt0, q + 1, __ATOMIC_RELAXED, __HIP_MEMORY_SCOPE_WORKGROUP);
      if (w < 7 && q >= 2) {
        const int rb = q - 2;
        asm volatile("s_waitcnt lgkmcnt(0)" ::: "memory");
        if (lane < 32) {
          const float v = ering1[(rb & 3) * 32 + lane];
          __hip_atomic_store(edgeG + (size_t)w * N + rb * 32 + lane, v,
                             __ATOMIC_RELAXED, __HIP_MEMORY_SCOPE_AGENT);
        }
        asm volatile("s_waitcnt vmcnt(0)" ::: "memory");
        if (lane == 0)
          (void)__hip_atomic_exchange(progG + w * PSTRIDE, rb + 1,
                                      __ATOMIC_RELAXED, __HIP_MEMORY_SCOPE_AGENT);
      }
    }
  }

  if (wv == 1 && w == 7 && lane == 63) out[0] = sqrtf(fmaxf(D3, 0.0f));
}

extern "C" void kernel_launch(void* const* d_in, const int* in_sizes, int n_in,
                              void* d_out, int out_size, void* d_ws, size_t ws_size,
                              hipStream_t stream) {
  const float* pred = (const float*)d_in[0];
  const float* tgt  = (const float*)d_in[1];
  char* ws = (char*)d_ws;
  u16* C2   = (u16*)ws;                                   // 32 MB
  float* na = (float*)(ws + (size_t)N * N * 2);
  float* nb = na + N;
  float* edgeG = nb + N;                                  // 16*N floats region
  int* progG = (int*)(edgeG + (size_t)16 * N);            // padded flags
  float* out = (float*)d_out;

  hipLaunchKernelGGL(norms_kernel, dim3(2048), dim3(256), 0, stream, pred, tgt, na, nb, progG);
  hipLaunchKernelGGL(gemm_kernel, dim3(32, 32), dim3(256), 0, stream, pred, tgt, na, nb, C2);
  hipLaunchKernelGGL(dp_kernel, dim3(8), dim3(128), 0, stream, C2, edgeG, progG, out);
}

// Round 7
// 659.211 us; speedup vs baseline: 1.0322x; 1.0322x over previous
//
#include <hip/hip_runtime.h>

typedef unsigned short u16;
typedef unsigned int u32;
typedef __bf16 bf16x8 __attribute__((ext_vector_type(8)));
typedef float f32x4 __attribute__((ext_vector_type(4)));

#define N 4096
#define KD 128
#define G 4              // cols per lane
#define W 256            // strip width (u16); 512B per row
#define CH 32            // rows per block
#define NCHUNK 128       // N/CH
#define NBLK 130         // ceil((N+63)/CH)
#define TOTSTEP 4159     // N + 63
#define WINROWS 128      // rolling window rows (4 slots x 32)
#define WINB 65536       // WINROWS*512
#define HUGEV 3.0e38f
#define TS 128
#define PADK 136
#define PSTRIDE 32       // prog padded to 128B

__device__ __forceinline__ u16 f2bf(float v) {
  u32 u = __float_as_uint(v);
  u += 0x7fffu + ((u >> 16) & 1u);   // RNE
  return (u16)(u >> 16);
}
__device__ __forceinline__ float bf2f(u16 b) { return __uint_as_float(((u32)b) << 16); }
__device__ __forceinline__ float bfround(float v) { return bf2f(f2bf(v)); }

__device__ __forceinline__ float dpp_shr1(float oldv, float src) {
  return __int_as_float(__builtin_amdgcn_update_dpp(
      __float_as_int(oldv), __float_as_int(src), 0x138, 0xF, 0xF, false));
}

__device__ __forceinline__ void gload_lds16(const void* g, void* l) {
  __builtin_amdgcn_global_load_lds((const __attribute__((address_space(1))) u32*)g,
                                   (__attribute__((address_space(3))) u32*)l, 16, 0, 0);
}

// ---------------- norms (of bf16-rounded points) + flag init ----------------
__global__ __launch_bounds__(256) void norms_kernel(const float* __restrict__ pred,
                                                    const float* __restrict__ tgt,
                                                    float* __restrict__ na, float* __restrict__ nb,
                                                    int* __restrict__ prog) {
  if (blockIdx.x == 0 && threadIdx.x < 16) prog[threadIdx.x * PSTRIDE] = 0;
  int gw = blockIdx.x * 4 + (threadIdx.x >> 6);
  int lane = threadIdx.x & 63;
  const float* base = (gw < N) ? (pred + (size_t)gw * KD) : (tgt + (size_t)(gw - N) * KD);
  float2 v = ((const float2*)base)[lane];
  float x = bfround(v.x), y = bfround(v.y);
  float s = x * x + y * y;
  #pragma unroll
  for (int off = 32; off > 0; off >>= 1) s += __shfl_xor(s, off);
  if (lane == 0) { if (gw < N) na[gw] = s; else nb[gw - N] = s; }
}

// ---------------- C2 = |a|^2 + |b|^2 - 2 a.b  (bf16 out) ----------------
__global__ __launch_bounds__(256) void gemm_kernel(const float* __restrict__ A, const float* __restrict__ B,
                                                   const float* __restrict__ na, const float* __restrict__ nb,
                                                   u16* __restrict__ C2) {
  __shared__ u16 As[TS * PADK];
  __shared__ u16 Bs[TS * PADK];
  const int bi = blockIdx.y, bj = blockIdx.x;
  const int tid = threadIdx.x;
  {
    int row = tid >> 1, half = (tid & 1) * 64;
    const float* ga = A + (size_t)(bi * TS + row) * KD + half;
    const float* gb = B + (size_t)(bj * TS + row) * KD + half;
    u16* la = As + row * PADK + half;
    u16* lb = Bs + row * PADK + half;
    #pragma unroll
    for (int v = 0; v < 16; ++v) {
      float4 fa = ((const float4*)ga)[v];
      float4 fb = ((const float4*)gb)[v];
      *(ushort4*)(la + v * 4) = make_ushort4(f2bf(fa.x), f2bf(fa.y), f2bf(fa.z), f2bf(fa.w));
      *(ushort4*)(lb + v * 4) = make_ushort4(f2bf(fb.x), f2bf(fb.y), f2bf(fb.z), f2bf(fb.w));
    }
  }
  __syncthreads();
  const int wid = tid >> 6, lane = tid & 63;
  const int wr = (wid >> 1) * 64, wc = (wid & 1) * 64;
  const int l15 = lane & 15, l4 = lane >> 4;
  f32x4 acc[4][4] = {};
  #pragma unroll
  for (int ks = 0; ks < 4; ++ks) {
    bf16x8 af[4], bq[4];
    const int ko = ks * 32 + l4 * 8;
    #pragma unroll
    for (int m = 0; m < 4; ++m) af[m] = *(const bf16x8*)(As + (wr + m * 16 + l15) * PADK + ko);
    #pragma unroll
    for (int n = 0; n < 4; ++n) bq[n] = *(const bf16x8*)(Bs + (wc + n * 16 + l15) * PADK + ko);
    #pragma unroll
    for (int m = 0; m < 4; ++m)
      #pragma unroll
      for (int n = 0; n < 4; ++n)
        acc[m][n] = __builtin_amdgcn_mfma_f32_16x16x32_bf16(af[m], bq[n], acc[m][n], 0, 0, 0);
  }
  #pragma unroll
  for (int m = 0; m < 4; ++m) {
    const int r0 = bi * TS + wr + m * 16 + l4 * 4;
    #pragma unroll
    for (int n = 0; n < 4; ++n) {
      const int col = bj * TS + wc + n * 16 + l15;
      const float nbv = nb[col];
      #pragma unroll
      for (int e = 0; e < 4; ++e) {
        const int r = r0 + e;
        float d2v = fmaxf(na[r] + nbv - 2.0f * acc[m][n][e], 0.0f);
        C2[(size_t)r * N + col] = f2bf(d2v);
      }
    }
  }
}

// ---------------- wavefront DP over squared distances ----------------
#define STEP_F(CU, EV) { \
  const float c0 = bf2f((CU).x), c1 = bf2f((CU).y), c2 = bf2f((CU).z), c3 = bf2f((CU).w); \
  const float Lc = dpp_shr1((EV), D3); \
  const float h0 = fmaxf(fminf(D0, Lp), c0); \
  const float h1 = fmaxf(fminf(D1, D0), c1); \
  const float h2 = fmaxf(fminf(D2, D1), c2); \
  const float h3 = fmaxf(fminf(D3, D2), c3); \
  float x = __builtin_amdgcn_fmed3f(Lc, c0, h0); D0 = x; \
  x = __builtin_amdgcn_fmed3f(x, c1, h1); D1 = x; \
  x = __builtin_amdgcn_fmed3f(x, c2, h2); D2 = x; \
  x = __builtin_amdgcn_fmed3f(x, c3, h3); D3 = x; \
  Lp = Lc; \
}

#define LDGRP(IX, GG) { \
  const int eo = (s_lo + 8 * (GG)) & emask; \
  ea2[IX] = *(const float4*)(esrc + eo); \
  eb2[IX] = *(const float4*)(esrc + eo + 4); \
  cv[IX][0] = *(const ushort4*)(clb + cbs); \
  cv[IX][1] = *(const ushort4*)(clb + cbs + 512); \
  cv[IX][2] = *(const ushort4*)(clb + cbs + 1024); \
  cv[IX][3] = *(const ushort4*)(clb + cbs + 1536); \
  cv[IX][4] = *(const ushort4*)(clb + cbs + 2048); \
  cv[IX][5] = *(const ushort4*)(clb + cbs + 2560); \
  cv[IX][6] = *(const ushort4*)(clb + cbs + 3072); \
  cv[IX][7] = *(const ushort4*)(clb + cbs + 3584); \
  cbs += 4096; if (cbs >= WINB) cbs -= WINB; \
}

#define CGRP(IX) { \
  float t0, t1, t2, t3, t4, t5, t6, t7; \
  STEP_F(cv[IX][0], ea2[IX].x); t0 = D3; \
  STEP_F(cv[IX][1], ea2[IX].y); t1 = D3; \
  STEP_F(cv[IX][2], ea2[IX].z); t2 = D3; \
  STEP_F(cv[IX][3], ea2[IX].w); t3 = D3; \
  STEP_F(cv[IX][4], eb2[IX].x); t4 = D3; \
  STEP_F(cv[IX][5], eb2[IX].y); t5 = D3; \
  STEP_F(cv[IX][6], eb2[IX].z); t6 = D3; \
  STEP_F(cv[IX][7], eb2[IX].w); t7 = D3; \
  if (wr63) { \
    *(float*)((char*)ringw + ( ewb       & 511)) = t0; \
    *(float*)((char*)ringw + ((ewb +  4) & 511)) = t1; \
    *(float*)((char*)ringw + ((ewb +  8) & 511)) = t2; \
    *(float*)((char*)ringw + ((ewb + 12) & 511)) = t3; \
    *(float*)((char*)ringw + ((ewb + 16) & 511)) = t4; \
    *(float*)((char*)ringw + ((ewb + 20) & 511)) = t5; \
    *(float*)((char*)ringw + ((ewb + 24) & 511)) = t6; \
    *(float*)((char*)ringw + ((ewb + 28) & 511)) = t7; \
  } \
  ewb += 32; \
}

__global__ __launch_bounds__(128) void dp_kernel(const u16* __restrict__ C2, float* __restrict__ edgeG,
                                                 int* __restrict__ progG, float* __restrict__ out) {
  __shared__ u16 winbuf[2][136 * 256];                 // 2 x 69632B rolling windows
  __shared__ __align__(16) float ering0[128];          // wave0 -> wave1 row ring
  __shared__ __align__(16) float ering1[128];          // wave1 private staging ring
  __shared__ __align__(16) float einG[2][32];          // wave0 edge input, double-buffered
  __shared__ int prodcnt0, conscnt0;

  const int w = blockIdx.x;
  const int tid = threadIdx.x, wv = tid >> 6, lane = tid & 63;
  const int S = 2 * w + wv;
  const u16* cbase = C2 + (size_t)S * W;
  u16* win = winbuf[wv];
  const char* clb = (const char*)win;
  float* ringw = wv ? ering1 : ering0;
  const bool prodrole = (wv == 0) || (w < 7);
  const bool wr63 = prodrole && (lane == 63);
  const int emask = wv ? 127 : 31;
  const bool s0 = (S == 0);
  const bool w1edge = (wv == 1) && (w < 7);

  if (tid == 0) { prodcnt0 = 0; conscnt0 = 0; }
  if (w == 0 && wv == 0 && lane < 32) {
    einG[0][lane] = (lane == 0) ? -HUGEV : HUGEV;   // row-0 seed in buf0
    einG[1][lane] = HUGEV;
  }
  __syncthreads();

  float D0 = HUGEV, D1 = HUGEV, D2 = HUGEV, D3 = HUGEV, Lp = HUGEV;

  auto STAGE = [&](int c) {
    const int lrow = lane >> 5, lcol = (lane & 31) * 8;
    const u16* g0 = cbase + (size_t)(c * CH + lrow) * N + lcol;
    u16* l0 = win + ((c * CH) & 127) * 256;
    #pragma unroll
    for (int n = 0; n < 16; ++n) gload_lds16(g0 + (size_t)(2 * n) * N, l0 + n * 512);
    if (((c * CH) & 127) == 0) {   // mirror rows 128..135 duplicate slot rows 0..7
      u16* lm = win + 128 * 256;
      #pragma unroll
      for (int n = 0; n < 4; ++n) gload_lds16(g0 + (size_t)(2 * n) * N, lm + n * 512);
    }
  };

  STAGE(0);
  STAGE(1);

  if (wv == 0 && w > 0) {           // prologue: edge rows for block 0
    if (lane == 0) {
      int it = 0; int* pg = progG + (w - 1) * PSTRIDE;
      while (__hip_atomic_fetch_add(pg, 0, __ATOMIC_RELAXED, __HIP_MEMORY_SCOPE_AGENT) < 1) {
        __builtin_amdgcn_s_sleep(2); if (++it > (1 << 22)) break;
      }
    }
    __builtin_amdgcn_fence(__ATOMIC_ACQUIRE, "agent");
    float ev0 = HUGEV;
    if (lane < 32)
      ev0 = __hip_atomic_load(edgeG + (size_t)(w - 1) * N + lane, __ATOMIC_RELAXED, __HIP_MEMORY_SCOPE_AGENT);
    if (lane < 32) einG[0][lane] = ev0;
  }

  for (int q = 0; q < NBLK; ++q) {
    const int s_lo = q * CH;
    const int s_hi = (s_lo + CH < TOTSTEP) ? (s_lo + CH) : TOTSTEP;

    // (A) wave1: early edge store for rb=q-3 (rows complete since end of block q-1)
    if (w1edge && q >= 3) {
      const int rb = q - 3;
      const float v = ering1[(rb & 3) * 32 + (lane & 31)];
      if (lane < 32)
        __hip_atomic_store(edgeG + (size_t)w * N + (size_t)rb * 32 + lane, v,
                           __ATOMIC_RELAXED, __HIP_MEMORY_SCOPE_AGENT);
    }

    // (B) polls
    if (wv == 1) {
      if (q <= 127) {
        int it = 0;
        while (__hip_atomic_load(&prodcnt0, __ATOMIC_ACQUIRE, __HIP_MEMORY_SCOPE_WORKGROUP) < q + 3) {
          __builtin_amdgcn_s_sleep(1); if (++it > (1 << 22)) break;
        }
      }
    } else {
      if (w > 0 && q + 1 <= 127) {        // prefetch-poll for block q+1's edge rows
        if (lane == 0) {
          int it = 0; int* pg = progG + (w - 1) * PSTRIDE;
          while (__hip_atomic_fetch_add(pg, 0, __ATOMIC_RELAXED, __HIP_MEMORY_SCOPE_AGENT) < q + 2) {
            __builtin_amdgcn_s_sleep(2); if (++it > (1 << 22)) break;
          }
        }
        __builtin_amdgcn_fence(__ATOMIC_ACQUIRE, "agent");
      }
      if (q >= 5) {                        // ring flow control
        int it = 0;
        while (__hip_atomic_load(&conscnt0, __ATOMIC_RELAXED, __HIP_MEMORY_SCOPE_WORKGROUP) < q - 4) {
          __builtin_amdgcn_s_sleep(1); if (++it > (1 << 22)) break;
        }
      }
    }

    // (C) top wait: STAGE(q) resident; counted so deeper prefetch stays in flight
    if (q >= 127) {
      asm volatile("s_waitcnt vmcnt(0)" ::: "memory");
    } else if (q < 3) {
      asm volatile("s_waitcnt vmcnt(16)" ::: "memory");
    } else if (w1edge) {
      if (q == 3)           { asm volatile("s_waitcnt vmcnt(21)" ::: "memory"); }
      else if ((q & 3) == 3){ asm volatile("s_waitcnt vmcnt(22)" ::: "memory"); }
      else                  { asm volatile("s_waitcnt vmcnt(18)" ::: "memory"); }
    } else {
      if ((q & 3) == 3)     { asm volatile("s_waitcnt vmcnt(20)" ::: "memory"); }
      else                  { asm volatile("s_waitcnt vmcnt(16)" ::: "memory"); }
    }
    __builtin_amdgcn_sched_barrier(0);

    // (D) wave0 w>0: issue edge load for block q+1 (committed to einG at block end)
    float ev = HUGEV;
    if (wv == 0 && w > 0 && q + 1 <= 127) {
      if (lane < 32)
        ev = __hip_atomic_load(edgeG + (size_t)(w - 1) * N + (size_t)(q + 1) * 32 + lane,
                               __ATOMIC_RELAXED, __HIP_MEMORY_SCOPE_AGENT);
    }
    if (s0 && wv == 0 && q == 1 && lane == 0) einG[0][0] = HUGEV;   // retire row-0 seed
    asm volatile("s_waitcnt lgkmcnt(0)" ::: "memory");
    __builtin_amdgcn_sched_barrier(0);

    // (E) compute
    const float* esrc = wv ? ering0 : einG[q & 1];
    u32 cbs = (((u32)(s_lo - lane)) & 127) * 512 + lane * 8;
    int ewb = (((s_lo - 63) & 127)) * 4;

    if (q >= 2 && q <= 127) {
      ushort4 cv[2][8];
      float4 ea2[2], eb2[2];
      LDGRP(0, 0)
      LDGRP(1, 1)
      CGRP(0)
      LDGRP(0, 2)
      CGRP(1)
      LDGRP(1, 3)
      CGRP(0)
      CGRP(1)
    } else {
      for (int s = s_lo; s < s_hi; ++s) {
        const ushort4 cu = *(const ushort4*)(clb + cbs);
        cbs += 512; if (cbs >= WINB) cbs -= WINB;
        const float evs = esrc[s & emask];
        const float c0 = bf2f(cu.x), c1 = bf2f(cu.y), c2 = bf2f(cu.z), c3 = bf2f(cu.w);
        const float Lc = dpp_shr1(evs, D3);
        const float h0 = fmaxf(fminf(D0, Lp), c0);
        const float h1 = fmaxf(fminf(D1, D0), c1);
        const float h2 = fmaxf(fminf(D2, D1), c2);
        const float h3 = fmaxf(fminf(D3, D2), c3);
        float x = __builtin_amdgcn_fmed3f(Lc, c0, h0);
        const float n0 = x;
        x = __builtin_amdgcn_fmed3f(x, c1, h1);
        const float n1 = x;
        x = __builtin_amdgcn_fmed3f(x, c2, h2);
        const float n2 = x;
        x = __builtin_amdgcn_fmed3f(x, c3, h3);
        const float n3 = x;
        const int ii = s - lane;
        const bool act = (u32)ii < (u32)N;
        Lp = (s0 && lane == 0) ? HUGEV : Lc;
        if (act) { D0 = n0; D1 = n1; D2 = n2; D3 = n3; }
        const int ie = s - 63;
        if (wr63 && ie >= 0) *(float*)((char*)ringw + ((ie & 127) * 4)) = n3;
      }
    }

    // (F) commit prefetched edge rows for block q+1
    if (wv == 0 && w > 0 && q + 1 <= 127 && lane < 32) einG[(q + 1) & 1][lane] = ev;

    // (G) publish + stage-ahead
    if (wv == 0) {
      if (lane == 0)
        __hip_atomic_store(&prodcnt0, q + 1, __ATOMIC_RELEASE, __HIP_MEMORY_SCOPE_WORKGROUP);
    } else {
      if (lane == 0)
        __hip_atomic_store(&conscnt0, q + 1, __ATOMIC_RELAXED, __HIP_MEMORY_SCOPE_WORKGROUP);
    }
    if (q + 2 <= 127) STAGE(q + 2);
    if (w1edge && q >= 3) {
      // counted wait: top edge store confirmed (had a full block); STAGE(q+2) stays in flight
      if (q >= 126)          { asm volatile("s_waitcnt vmcnt(0)"  ::: "memory"); }
      else if ((q & 3) == 2) { asm volatile("s_waitcnt vmcnt(20)" ::: "memory"); }
      else                   { asm volatile("s_waitcnt vmcnt(16)" ::: "memory"); }
      if (lane == 0)
        __hip_atomic_store(progG + w * PSTRIDE, q - 2, __ATOMIC_RELAXED, __HIP_MEMORY_SCOPE_AGENT);
    }
    if (w1edge && q == 129) {   // final row-block rb=127
      asm volatile("s_waitcnt lgkmcnt(0)" ::: "memory");
      const float v = ering1[96 + (lane & 31)];
      if (lane < 32)
        __hip_atomic_store(edgeG + (size_t)w * N + 4064 + lane, v,
                           __ATOMIC_RELAXED, __HIP_MEMORY_SCOPE_AGENT);
      asm volatile("s_waitcnt vmcnt(0)" ::: "memory");
      if (lane == 0)
        __hip_atomic_store(progG + w * PSTRIDE, 128, __ATOMIC_RELAXED, __HIP_MEMORY_SCOPE_AGENT);
    }
  }

  if (wv == 1 && w == 7 && lane == 63) out[0] = sqrtf(fmaxf(D3, 0.0f));
}

extern "C" void kernel_launch(void* const* d_in, const int* in_sizes, int n_in,
                              void* d_out, int out_size, void* d_ws, size_t ws_size,
                              hipStream_t stream) {
  const float* pred = (const float*)d_in[0];
  const float* tgt  = (const float*)d_in[1];
  char* ws = (char*)d_ws;
  u16* C2   = (u16*)ws;                                   // 32 MB
  float* na = (float*)(ws + (size_t)N * N * 2);
  float* nb = na + N;
  float* edgeG = nb + N;
  int* progG = (int*)(edgeG + (size_t)16 * N);
  float* out = (float*)d_out;

  hipLaunchKernelGGL(norms_kernel, dim3(2048), dim3(256), 0, stream, pred, tgt, na, nb, progG);
  hipLaunchKernelGGL(gemm_kernel, dim3(32, 32), dim3(256), 0, stream, pred, tgt, na, nb, C2);
  hipLaunchKernelGGL(dp_kernel, dim3(8), dim3(128), 0, stream, C2, edgeG, progG, out);
}